// Round 3
// baseline (230.660 us; speedup 1.0000x reference)
//
#include <hip/hip_runtime.h>
#include <math.h>

#define BATCH_  256
#define NTOT    16384
#define ETOT    524288

typedef __attribute__((ext_vector_type(8))) short short8v;
typedef __attribute__((ext_vector_type(2))) unsigned short ushort2v;
typedef __attribute__((ext_vector_type(4))) float f32x4;
typedef __attribute__((ext_vector_type(2))) float f32x2;

#define MFMA16(a,b,c) __builtin_amdgcn_mfma_f32_16x16x32_bf16((a),(b),(c),0,0,0)

__device__ __forceinline__ unsigned short f2bf(float f) {
    unsigned int x = __float_as_uint(f);
    return (unsigned short)((x + 0x7fffu + ((x >> 16) & 1u)) >> 16);
}
__device__ __forceinline__ float bf2f(unsigned short h) {
    return __uint_as_float(((unsigned int)h) << 16);
}
__device__ __forceinline__ float softplus_f(float v) {
    return v > 20.f ? v : log1pf(expf(v));
}

// ---------------------------------------------------------------------------
// K1: xw[g][0:256]   = x[g] @ W1[0:64]    (xi part)
//     xw[g][256:512] = x[g] @ W1[64:128]  (xj part)
// ---------------------------------------------------------------------------
__global__ __launch_bounds__(256) void k_xw(const float* __restrict__ x,
                                            const float* __restrict__ W1,
                                            float* __restrict__ xw) {
    const int nb = blockIdx.x * 16;
    const int t  = threadIdx.x;
    __shared__ float xs[16][64];
    for (int i = t; i < 16 * 64; i += 256)
        xs[i >> 6][i & 63] = x[(size_t)(nb + (i >> 6)) * 64 + (i & 63)];
    __syncthreads();

    float acc_a[16], acc_b[16];
#pragma unroll
    for (int i = 0; i < 16; i++) { acc_a[i] = 0.f; acc_b[i] = 0.f; }

    for (int k = 0; k < 64; k++) {
        const float wa = W1[k * 256 + t];
        const float wb = W1[(64 + k) * 256 + t];
#pragma unroll
        for (int i = 0; i < 16; i++) {
            const float xv = xs[i][k];
            acc_a[i] = fmaf(xv, wa, acc_a[i]);
            acc_b[i] = fmaf(xv, wb, acc_b[i]);
        }
    }
#pragma unroll
    for (int i = 0; i < 16; i++) {
        xw[(size_t)(nb + i) * 512 + t]       = acc_a[i];
        xw[(size_t)(nb + i) * 512 + 256 + t] = acc_b[i];
    }
}

// ---------------------------------------------------------------------------
// K2: offset-form edge kernel. Block = 1 batch, 1024 thr (16 waves).
// Wave (ng=w&3, cq=w>>2): lane owns node = ng*16 + (l&15), chs cb..cb+3 for
// cht = cq*4+i. For each offset o (edge o of every node):
//   D_o = mfma(W1c^T_frag, ea_o^T_frag, C=xa+b1)  (split bf16, 3 mfma)
//   acc += relu(D_o + xw_b[dst(node,o)])          (in-register, no shuffles)
// ea_o slice packed hi/lo in double-buffered LDS; xw_b gathered from L1/L2.
// ---------------------------------------------------------------------------
__global__ __launch_bounds__(1024) void k_edges3(
    const float* __restrict__ xw, const float* __restrict__ ea,
    const int* __restrict__ dst, const float* __restrict__ W1,
    const float* __restrict__ b1, float* __restrict__ sumh1)
{
    const int b   = blockIdx.x;
    const int tid = threadIdx.x;
    const int l   = tid & 63, w = tid >> 6;
    const int g   = l >> 4, l15 = l & 15;
    const int ng  = w & 3, cq = w >> 2;

    __shared__ unsigned short s_w1c[2][16][64][8];    // 32 KB [hl][cht][lane][j]
    __shared__ unsigned short s_ea[2][2][4][64][8];   // 16 KB [buf][hl][ng][lane][j]
    __shared__ unsigned char  s_dstl[2048];

    // ---- stage W1c fragments (hi/lo)
    for (int idx = tid; idx < 16 * 64 * 8; idx += 1024) {
        const int cht = idx >> 9, rem = idx & 511, ll = rem >> 3, j = rem & 7;
        const int k = ((ll >> 4) << 3) + j, c = cht * 16 + (ll & 15);
        const float v = W1[(128 + k) * 256 + c];
        const unsigned short h = f2bf(v);
        s_w1c[0][cht][ll][j] = h;
        s_w1c[1][cht][ll][j] = (unsigned short)f2bf(v - bf2f(h));
    }
    for (int idx = tid; idx < 2048; idx += 1024)
        s_dstl[idx] = (unsigned char)(dst[b * 2048 + idx] & 63);

    // ---- ea staging geometry (thread handles 2 values of each o-slice)
    const int sn  = tid >> 4;            // node 0..63
    const int sk  = (tid & 15) * 2;      // k 0,2,..,30
    const int sng = sn >> 4;
    const int sll = ((sk >> 3) << 4) | (sn & 15);
    const int sj  = sk & 7;
    const size_t eabase = (size_t)b * 65536 + (size_t)sn * 1024 + sk;

    {   // stage slice o=0
        const f32x2 v = *(const f32x2*)&ea[eabase];
        const unsigned short h0 = f2bf(v[0]), h1 = f2bf(v[1]);
        ushort2v hi = {h0, h1};
        ushort2v lo = {(unsigned short)f2bf(v[0] - bf2f(h0)),
                       (unsigned short)f2bf(v[1] - bf2f(h1))};
        *(ushort2v*)&s_ea[0][0][sng][sll][sj] = hi;
        *(ushort2v*)&s_ea[0][1][sng][sll][sj] = lo;
    }
    __syncthreads();

    // ---- per-wave invariants
    short8v Ah[4], Al[4];
#pragma unroll
    for (int i = 0; i < 4; i++) {
        Ah[i] = *(const short8v*)&s_w1c[0][cq * 4 + i][l][0];
        Al[i] = *(const short8v*)&s_w1c[1][cq * 4 + i][l][0];
    }

    const int node = ng * 16 + l15;
    const size_t grow = (size_t)b * 64 + node;
    f32x4 xab1[4];
#pragma unroll
    for (int i = 0; i < 4; i++) {
        const int cb = (cq * 4 + i) * 16 + g * 4;
        const f32x4 xa = *(const f32x4*)&xw[grow * 512 + cb];
        const f32x4 bv = *(const f32x4*)&b1[cb];
        xab1[i] = xa + bv;
    }

    const float* xwb = xw + (size_t)b * 64 * 512 + 256 + cq * 64 + g * 4;

    f32x4 acc[4];
#pragma unroll
    for (int i = 0; i < 4; i++) acc[i] = (f32x4){0.f, 0.f, 0.f, 0.f};

#pragma unroll 2
    for (int o = 0; o < 32; o++) {
        f32x2 pv;
        if (o < 31) pv = *(const f32x2*)&ea[eabase + (size_t)(o + 1) * 32];

        const int buf = o & 1;
        const short8v Bh = *(const short8v*)&s_ea[buf][0][ng][l][0];
        const short8v Bl = *(const short8v*)&s_ea[buf][1][ng][l][0];

        const int d = s_dstl[node * 32 + o];
        const float* wr = xwb + (size_t)d * 512;
        const f32x4 wb0 = *(const f32x4*)(wr);
        const f32x4 wb1 = *(const f32x4*)(wr + 16);
        const f32x4 wb2 = *(const f32x4*)(wr + 32);
        const f32x4 wb3 = *(const f32x4*)(wr + 48);

        f32x4 d0 = MFMA16(Al[0], Bh, xab1[0]);
        d0 = MFMA16(Ah[0], Bl, d0);
        d0 = MFMA16(Ah[0], Bh, d0);
        f32x4 d1 = MFMA16(Al[1], Bh, xab1[1]);
        d1 = MFMA16(Ah[1], Bl, d1);
        d1 = MFMA16(Ah[1], Bh, d1);
        f32x4 d2 = MFMA16(Al[2], Bh, xab1[2]);
        d2 = MFMA16(Ah[2], Bl, d2);
        d2 = MFMA16(Ah[2], Bh, d2);
        f32x4 d3 = MFMA16(Al[3], Bh, xab1[3]);
        d3 = MFMA16(Ah[3], Bl, d3);
        d3 = MFMA16(Ah[3], Bh, d3);

#pragma unroll
        for (int r = 0; r < 4; r++) {
            acc[0][r] += fmaxf(d0[r] + wb0[r], 0.f);
            acc[1][r] += fmaxf(d1[r] + wb1[r], 0.f);
            acc[2][r] += fmaxf(d2[r] + wb2[r], 0.f);
            acc[3][r] += fmaxf(d3[r] + wb3[r], 0.f);
        }

        if (o < 31) {
            const unsigned short h0 = f2bf(pv[0]), h1 = f2bf(pv[1]);
            ushort2v hi = {h0, h1};
            ushort2v lo = {(unsigned short)f2bf(pv[0] - bf2f(h0)),
                           (unsigned short)f2bf(pv[1] - bf2f(h1))};
            *(ushort2v*)&s_ea[buf ^ 1][0][sng][sll][sj] = hi;
            *(ushort2v*)&s_ea[buf ^ 1][1][sng][sll][sj] = lo;
        }
        __syncthreads();
    }

#pragma unroll
    for (int i = 0; i < 4; i++) {
        const int cb = (cq * 4 + i) * 16 + g * 4;
        *(f32x4*)&sumh1[grow * 256 + cb] = acc[i];
    }
}

// ---------------------------------------------------------------------------
// K3: agg = sum_h1 @ W2 + 32*b2, split-bf16 MFMA (unchanged from round 2).
// ---------------------------------------------------------------------------
__global__ __launch_bounds__(512) void k_agg(
    const float* __restrict__ sumh1, const float* __restrict__ W2,
    const float* __restrict__ b2, float* __restrict__ agg)
{
    const int bx = blockIdx.x;
    const int rcb = bx >> 1, chalf = bx & 1;
    const int tid = threadIdx.x;
    const int l = tid & 63, w = tid >> 6, g = l >> 4, l15 = l & 15;

    __shared__ unsigned short s_w2[2][8][8][64][8];   // 128 KB

    for (int idx = tid; idx < 8 * 8 * 64 * 8; idx += 512) {
        const int ks = idx >> 12, ct = (idx >> 9) & 7, ll = (idx >> 3) & 63, j = idx & 7;
        const int k = ks * 32 + ((ll >> 4) << 3) + j;
        const int c = chalf * 128 + ct * 16 + (ll & 15);
        const float v = W2[k * 256 + c];
        const unsigned short h = f2bf(v);
        s_w2[0][ks][ct][ll][j] = h;
        s_w2[1][ks][ct][ll][j] = (unsigned short)f2bf(v - bf2f(h));
    }
    __syncthreads();

    const int row0 = rcb * 128 + w * 16;
    f32x4 acc[8];
#pragma unroll
    for (int ct = 0; ct < 8; ct++) acc[ct] = (f32x4){0.f, 0.f, 0.f, 0.f};

    for (int ks = 0; ks < 8; ks++) {
        const float* p = sumh1 + (size_t)(row0 + l15) * 256 + ks * 32 + g * 8;
        short8v Ahh, All;
        {
            const f32x4 a = *(const f32x4*)p;
            const f32x4 q = *(const f32x4*)(p + 4);
            float v[8] = {a[0], a[1], a[2], a[3], q[0], q[1], q[2], q[3]};
#pragma unroll
            for (int j = 0; j < 8; j++) {
                const unsigned short h = f2bf(v[j]);
                Ahh[j] = (short)h;
                All[j] = (short)f2bf(v[j] - bf2f(h));
            }
        }
#pragma unroll
        for (int ct = 0; ct < 8; ct++) {
            const short8v Bh = *(const short8v*)&s_w2[0][ks][ct][l][0];
            const short8v Bl = *(const short8v*)&s_w2[1][ks][ct][l][0];
            acc[ct] = MFMA16(Ahh, Bh, acc[ct]);
            acc[ct] = MFMA16(Ahh, Bl, acc[ct]);
            acc[ct] = MFMA16(All, Bh, acc[ct]);
        }
    }
#pragma unroll
    for (int ct = 0; ct < 8; ct++) {
        const int c = chalf * 128 + ct * 16 + l15;
        const float bb = 32.f * b2[c];
#pragma unroll
        for (int r = 0; r < 4; r++)
            agg[(size_t)(row0 + g * 4 + r) * 256 + c] = acc[ct][r] + bb;
    }
}

// ---------------------------------------------------------------------------
// K4: heads, factored: u[n] = dot(xpp[n], W[0:320]), v[n] = dot(xpp[n],
// W[320:640]); head z = u[e0] + v[e1] + b. x/agg staged in padded LDS.
// ---------------------------------------------------------------------------
__global__ __launch_bounds__(256) void k_head2(
    const float* __restrict__ x, const float* __restrict__ agg,
    const int* __restrict__ edges, const float* __restrict__ high,
    const float* __restrict__ Wmu,  const float* __restrict__ bmu,
    const float* __restrict__ Wsig, const float* __restrict__ bsig,
    const float* __restrict__ Wmu2, const float* __restrict__ bmu2,
    const float* __restrict__ Wsig2,const float* __restrict__ bsig2,
    float* __restrict__ out)
{
    const int b = blockIdx.x, t = threadIdx.x;
    __shared__ float sx[64][68];    // ~17 KB, pad 68 -> 2-way banks
    __shared__ float sa[64][260];   // ~65 KB, pad 260 -> 2-way banks
    __shared__ float su[64][4];     // u_mu, u_sig, v_mu, v_sig
    __shared__ float su2[8][2];

    for (int i = t; i < 64 * 16; i += 256) {
        const int n = i >> 4, kq = i & 15;
        *(f32x4*)&sx[n][kq * 4] = *(const f32x4*)&x[((size_t)b * 64 + n) * 64 + kq * 4];
    }
    for (int i = t; i < 64 * 64; i += 256) {
        const int n = i >> 6, kq = i & 63;
        *(f32x4*)&sa[n][kq * 4] = *(const f32x4*)&agg[((size_t)b * 64 + n) * 256 + kq * 4];
    }
    __syncthreads();

    {
        const int n = t >> 2, s = t & 3;
        const float* Wb = (s & 1) ? Wsig : Wmu;
        const float* Wp = Wb + ((s >> 1) ? 320 : 0);
        float z = 0.f;
        for (int k = 0; k < 64; k++)  z = fmaf(sx[n][k], Wp[k], z);
        for (int k = 0; k < 256; k++) z = fmaf(sa[n][k], Wp[64 + k], z);
        su[n][s] = z;
    }
    if (t < 16) {
        const int n = 56 + (t >> 1), s = t & 1;
        const float* Wp = s ? Wsig2 : Wmu2;
        float z = 0.f;
        for (int k = 0; k < 64; k++)  z = fmaf(sx[n][k], Wp[k], z);
        for (int k = 0; k < 256; k++) z = fmaf(sa[n][k], Wp[64 + k], z);
        su2[n - 56][s] = z;
    }
    __syncthreads();

    if (t < 128) {
        const int e0 = edges[t * 2], e1 = edges[t * 2 + 1];
        const float a  = softplus_f(su[e0][0] + su[e1][2] + bmu[0])  + 1e-20f;
        const float be = softplus_f(su[e0][1] + su[e1][3] + bsig[0]) + 1e-20f;
        out[(size_t)b * 136 + t] = a / (a + be) * high[t];
    } else if (t < 136) {
        const int j = t - 128;
        const float a  = softplus_f(su2[j][0] + bmu2[0])  + 1e-20f;
        const float be = softplus_f(su2[j][1] + bsig2[0]) + 1e-20f;
        out[(size_t)b * 136 + t] = a / (a + be) * high[128 + j];
    }
}

// ---------------------------------------------------------------------------
extern "C" void kernel_launch(void* const* d_in, const int* in_sizes, int n_in,
                              void* d_out, int out_size, void* d_ws, size_t ws_size,
                              hipStream_t stream) {
    const float* x     = (const float*)d_in[0];
    const int*   eidx  = (const int*)  d_in[1];
    const float* ea    = (const float*)d_in[2];
    const int*   edges = (const int*)  d_in[3];
    const float* high  = (const float*)d_in[4];
    const float* W1    = (const float*)d_in[5];
    const float* b1    = (const float*)d_in[6];
    const float* W2    = (const float*)d_in[7];
    const float* b2    = (const float*)d_in[8];
    const float* Wmu   = (const float*)d_in[9];
    const float* bmu   = (const float*)d_in[10];
    const float* Wsig  = (const float*)d_in[11];
    const float* bsig  = (const float*)d_in[12];
    const float* Wmu2  = (const float*)d_in[13];
    const float* bmu2  = (const float*)d_in[14];
    const float* Wsig2 = (const float*)d_in[15];
    const float* bsig2 = (const float*)d_in[16];
    float* out = (float*)d_out;

    // ws: xw (16384*512 f32, 33.5 MB) | sumh1 (16384*256 f32, 16.8 MB)
    // agg aliases xw (dead after k_edges3).
    float* xw    = (float*)d_ws;
    float* sumh1 = xw + (size_t)NTOT * 512;
    float* agg   = xw;
    const int* dst = eidx + ETOT;

    hipLaunchKernelGGL(k_xw,     dim3(NTOT / 16), dim3(256),  0, stream, x, W1, xw);
    hipLaunchKernelGGL(k_edges3, dim3(BATCH_),    dim3(1024), 0, stream,
                       xw, ea, dst, W1, b1, sumh1);
    hipLaunchKernelGGL(k_agg,    dim3(256),       dim3(512),  0, stream,
                       sumh1, W2, b2, agg);
    hipLaunchKernelGGL(k_head2,  dim3(BATCH_),    dim3(256),  0, stream,
                       x, agg, edges, high,
                       Wmu, bmu, Wsig, bsig, Wmu2, bmu2, Wsig2, bsig2, out);
}

// Round 4
// 171.407 us; speedup vs baseline: 1.3457x; 1.3457x over previous
//
#include <hip/hip_runtime.h>
#include <math.h>

#define BATCH_  256
#define NTOT    16384
#define ETOT    524288

typedef __attribute__((ext_vector_type(8))) short short8v;
typedef __attribute__((ext_vector_type(4))) float f32x4;

#define MFMA16(a,b,c) __builtin_amdgcn_mfma_f32_16x16x32_bf16((a),(b),(c),0,0,0)

__device__ __forceinline__ unsigned short f2bf(float f) {
    unsigned int x = __float_as_uint(f);
    return (unsigned short)((x + 0x7fffu + ((x >> 16) & 1u)) >> 16);
}
__device__ __forceinline__ float bf2f(unsigned short h) {
    return __uint_as_float(((unsigned int)h) << 16);
}
__device__ __forceinline__ float softplus_f(float v) {
    return v > 20.f ? v : log1pf(expf(v));
}
__device__ __forceinline__ float dot4(f32x4 a, f32x4 b) {
    float z = a[0] * b[0];
    z = fmaf(a[1], b[1], z);
    z = fmaf(a[2], b[2], z);
    z = fmaf(a[3], b[3], z);
    return z;
}

// ---------------------------------------------------------------------------
// K0: pre-pack split-bf16 (hi/lo) MFMA fragments of W1 (160x256, 5 k-tiles)
// and W2 (256x256, 8 k-tiles) into ws. Unit = (ktile, cht): 2KB each.
// frag layout (shorts): unit*1024 + hl*512 + l*8 + j, where the fragment
// value for lane l, slot j is W[(rowbase + (l>>4)*8 + j)*256 + cht*16+(l&15)].
// Units 0..79 = W1 (kt=u>>4), 80..207 = W2.
// ---------------------------------------------------------------------------
__global__ __launch_bounds__(256) void k_prep(const float* __restrict__ W1,
                                              const float* __restrict__ W2,
                                              unsigned short* __restrict__ frags) {
    const int u = blockIdx.x;
    const float* S = (u < 80) ? W1 : W2;
    const int ul = (u < 80) ? u : (u - 80);
    const int rowbase = (ul >> 4) * 32;
    const int cht = ul & 15;
    for (int idx = threadIdx.x; idx < 512; idx += 256) {
        const int l = idx >> 3, j = idx & 7;
        const int row = rowbase + ((l >> 4) << 3) + j;
        const int col = cht * 16 + (l & 15);
        const float v = S[row * 256 + col];
        const unsigned short h = f2bf(v);
        frags[u * 1024 + idx]       = h;
        frags[u * 1024 + 512 + idx] = f2bf(v - bf2f(h));
    }
}

// ---------------------------------------------------------------------------
// K1: xw = x @ W1[0:128] via split-bf16 MFMA.
// Block = 128 rows x 256 cols (colhalf), 512 thr (8 waves, 16 rows each).
// B-fragments read directly from prepped ws (L2-hot).
// ---------------------------------------------------------------------------
__global__ __launch_bounds__(512) void k_xw2(const float* __restrict__ x,
                                             const unsigned short* __restrict__ frags,
                                             float* __restrict__ xw) {
    const int bx = blockIdx.x;
    const int rowblk = bx >> 1, chalf = bx & 1;
    const int tid = threadIdx.x;
    const int l = tid & 63, w = tid >> 6, g = l >> 4, l15 = l & 15;
    const int row0 = rowblk * 128 + w * 16;

    // A-fragments: x rows, k-tiles 0,1 (k = kt*32 + g*8 + j), hi/lo
    short8v Axh[2], Axl[2];
#pragma unroll
    for (int kt = 0; kt < 2; kt++) {
        const float* p = x + (size_t)(row0 + l15) * 64 + kt * 32 + g * 8;
        const f32x4 a = *(const f32x4*)p;
        const f32x4 q = *(const f32x4*)(p + 4);
        float v[8] = {a[0], a[1], a[2], a[3], q[0], q[1], q[2], q[3]};
#pragma unroll
        for (int j = 0; j < 8; j++) {
            const unsigned short h = f2bf(v[j]);
            Axh[kt][j] = (short)h;
            Axl[kt][j] = (short)f2bf(v[j] - bf2f(h));
        }
    }

    f32x4 acc[16];
#pragma unroll
    for (int i = 0; i < 16; i++) acc[i] = (f32x4){0.f, 0.f, 0.f, 0.f};

#pragma unroll
    for (int i = 0; i < 16; i++) {
        const int ct = chalf * 16 + i;           // output col-tile 0..31
#pragma unroll
        for (int kk = 0; kk < 2; kk++) {
            const int u = (chalf * 2 + kk) * 16 + (ct & 15);   // W1 k-tile unit
            const short8v Bh = *(const short8v*)&frags[u * 1024 + l * 8];
            const short8v Bl = *(const short8v*)&frags[u * 1024 + 512 + l * 8];
            acc[i] = MFMA16(Axl[kk], Bh, acc[i]);
            acc[i] = MFMA16(Axh[kk], Bl, acc[i]);
            acc[i] = MFMA16(Axh[kk], Bh, acc[i]);
        }
    }
#pragma unroll
    for (int i = 0; i < 16; i++) {
        const int ct = chalf * 16 + i;
#pragma unroll
        for (int r = 0; r < 4; r++)
            xw[(size_t)(row0 + g * 4 + r) * 512 + ct * 16 + l15] = acc[i][r];
    }
}

// ---------------------------------------------------------------------------
// K2: offset-form edge kernel, LDS-gather version. Block = 1 batch, 16 waves.
// Wave (ng=w&3, cq=w>>2): lane owns node = ng*16 + l15, channels cb..cb+3 for
// i=0..3 (cb = cq*64+i*16+g*4). Per offset o:
//   D = mfma(W1c^T, ea_o^T, C = xa + b1)   (split bf16, 3 mfma, C-folded)
//   acc += relu(D + s_xwb[dst(node,o)])    (swizzled LDS gather, 2-way free)
// ea staged hi/lo in LDS in 4-offset chunks (coalesced global, issue-early).
// ---------------------------------------------------------------------------
__global__ __launch_bounds__(1024) void k_edges4(
    const float* __restrict__ xw, const float* __restrict__ ea,
    const int* __restrict__ dst, const float* __restrict__ b1,
    const unsigned short* __restrict__ frags, float* __restrict__ sumh1)
{
    const int b   = blockIdx.x;
    const int tid = threadIdx.x;
    const int l   = tid & 63, w = tid >> 6;
    const int g   = l >> 4, l15 = l & 15;
    const int ng  = w & 3, cq = w >> 2;

    __shared__ float          s_xwb[64][256];         // 64 KB, XOR-swizzled
    __shared__ unsigned short s_ea[4][2][4][64][8];   // 32 KB [ol][hl][ng][l][j]
    __shared__ unsigned char  s_dstl[2048];           // 2 KB

    // ---- stage xwb (swizzled) + dst local ids
    for (int idx = tid; idx < 4096; idx += 1024) {
        const int d = idx >> 6, c4 = (idx & 63) * 4;
        const f32x4 v = *(const f32x4*)&xw[(size_t)(b * 64 + d) * 512 + 256 + c4];
        *(f32x4*)&s_xwb[d][c4 ^ ((d & 7) << 2)] = v;
    }
    for (int idx = tid; idx < 2048; idx += 1024)
        s_dstl[idx] = (unsigned char)(dst[b * 2048 + idx] & 63);

    // ---- per-wave W1c^T fragments from prepped ws (units 64..79)
    short8v Ah[4], Al[4];
#pragma unroll
    for (int i = 0; i < 4; i++) {
        const int base = (64 + cq * 4 + i) * 1024 + l * 8;
        Ah[i] = *(const short8v*)&frags[base];
        Al[i] = *(const short8v*)&frags[base + 512];
    }

    const int node = ng * 16 + l15;
    const size_t grow = (size_t)b * 64 + node;
    f32x4 xab1[4];
#pragma unroll
    for (int i = 0; i < 4; i++) {
        const int cb = cq * 64 + i * 16 + g * 4;
        xab1[i] = *(const f32x4*)&xw[grow * 512 + cb] + *(const f32x4*)&b1[cb];
    }

    // ---- ea chunk staging geometry: thread -> (o-slice ols, node ns, k-octet)
    const int ols = tid >> 8;
    const int ns  = (tid & 255) >> 2;
    const int ko  = tid & 3;
    const int sll = (ko << 4) | (ns & 15);
    const int sng = ns >> 4;
    const float* eab = ea + (size_t)b * 65536 + (size_t)ns * 1024 + ko * 8;

    __syncthreads();   // staging of s_xwb / s_dstl complete

    // prologue: load chunk 0 (o = ols)
    f32x4 ld0 = *(const f32x4*)&eab[ols * 32];
    f32x4 ld1 = *(const f32x4*)&eab[ols * 32 + 4];

    f32x4 acc[4];
#pragma unroll
    for (int i = 0; i < 4; i++) acc[i] = (f32x4){0.f, 0.f, 0.f, 0.f};

    for (int c = 0; c < 8; c++) {
        // pack the staged slice (waits on the outstanding global loads)
        short8v hi, lo;
        {
            float v[8] = {ld0[0], ld0[1], ld0[2], ld0[3],
                          ld1[0], ld1[1], ld1[2], ld1[3]};
#pragma unroll
            for (int j = 0; j < 8; j++) {
                const unsigned short h = f2bf(v[j]);
                hi[j] = (short)h;
                lo[j] = (short)f2bf(v[j] - bf2f(h));
            }
        }
        __syncthreads();                       // previous chunk fully consumed
        *(short8v*)&s_ea[ols][0][sng][sll][0] = hi;
        *(short8v*)&s_ea[ols][1][sng][sll][0] = lo;
        __syncthreads();                       // chunk visible

        if (c < 7) {                            // issue next chunk early
            const int on = (c + 1) * 4 + ols;
            ld0 = *(const f32x4*)&eab[on * 32];
            ld1 = *(const f32x4*)&eab[on * 32 + 4];
        }

        const unsigned int dwc = ((const unsigned int*)s_dstl)[node * 8 + c];

#pragma unroll
        for (int ol = 0; ol < 4; ol++) {
            const short8v Bh = *(const short8v*)&s_ea[ol][0][ng][l][0];
            const short8v Bl = *(const short8v*)&s_ea[ol][1][ng][l][0];
            const int d = (dwc >> (ol * 8)) & 0xFF;
            const int swz = (d & 7) << 2;

#pragma unroll
            for (int i = 0; i < 4; i++) {
                const int cb = cq * 64 + i * 16 + g * 4;
                const f32x4 wb = *(const f32x4*)&s_xwb[d][cb ^ swz];
                f32x4 di = MFMA16(Al[i], Bh, xab1[i]);
                di = MFMA16(Ah[i], Bl, di);
                di = MFMA16(Ah[i], Bh, di);
#pragma unroll
                for (int r = 0; r < 4; r++)
                    acc[i][r] += fmaxf(di[r] + wb[r], 0.f);
            }
        }
    }

#pragma unroll
    for (int i = 0; i < 4; i++)
        *(f32x4*)&sumh1[grow * 256 + cq * 64 + i * 16 + g * 4] = acc[i];
}

// ---------------------------------------------------------------------------
// K3: agg = sum_h1 @ W2 + 32*b2. Block = 128 rows x 128 cols, 512 thr.
// W2 fragments block-copied pre-packed from ws into LDS (no per-block f2bf).
// ---------------------------------------------------------------------------
__global__ __launch_bounds__(512) void k_agg3(
    const float* __restrict__ sumh1, const unsigned short* __restrict__ frags,
    const float* __restrict__ b2, float* __restrict__ agg)
{
    const int bx = blockIdx.x;
    const int rcb = bx >> 1, chalf = bx & 1;
    const int tid = threadIdx.x;
    const int l = tid & 63, w = tid >> 6, g = l >> 4, l15 = l & 15;

    __shared__ unsigned short s_w2[64 * 1024];   // 128 KB: [kt*8+ct][hl][l][j]

    for (int i = tid; i < 8192; i += 512) {
        const int unit_l = i >> 7;               // kt*8 + ct
        const int part = (i & 127) * 8;
        const int u = 80 + (unit_l >> 3) * 16 + chalf * 8 + (unit_l & 7);
        *(short8v*)&s_w2[unit_l * 1024 + part] =
            *(const short8v*)&frags[u * 1024 + part];
    }
    __syncthreads();

    const int row0 = rcb * 128 + w * 16;
    f32x4 acc[8];
#pragma unroll
    for (int ct = 0; ct < 8; ct++) acc[ct] = (f32x4){0.f, 0.f, 0.f, 0.f};

    for (int ks = 0; ks < 8; ks++) {
        const float* p = sumh1 + (size_t)(row0 + l15) * 256 + ks * 32 + g * 8;
        short8v Ahh, All;
        {
            const f32x4 a = *(const f32x4*)p;
            const f32x4 q = *(const f32x4*)(p + 4);
            float v[8] = {a[0], a[1], a[2], a[3], q[0], q[1], q[2], q[3]};
#pragma unroll
            for (int j = 0; j < 8; j++) {
                const unsigned short h = f2bf(v[j]);
                Ahh[j] = (short)h;
                All[j] = (short)f2bf(v[j] - bf2f(h));
            }
        }
#pragma unroll
        for (int ct = 0; ct < 8; ct++) {
            const short8v Bh = *(const short8v*)&s_w2[(ks * 8 + ct) * 1024 + l * 8];
            const short8v Bl = *(const short8v*)&s_w2[(ks * 8 + ct) * 1024 + 512 + l * 8];
            acc[ct] = MFMA16(Ahh, Bh, acc[ct]);
            acc[ct] = MFMA16(Ahh, Bl, acc[ct]);
            acc[ct] = MFMA16(All, Bh, acc[ct]);
        }
    }
#pragma unroll
    for (int ct = 0; ct < 8; ct++) {
        const int cc = chalf * 128 + ct * 16 + l15;
        const float bb = 32.f * b2[cc];
#pragma unroll
        for (int r = 0; r < 4; r++)
            agg[(size_t)(row0 + g * 4 + r) * 256 + cc] = acc[ct][r] + bb;
    }
}

// ---------------------------------------------------------------------------
// K4: heads, factored u/v form, f32x4-vectorized dots.
// ---------------------------------------------------------------------------
__global__ __launch_bounds__(256) void k_head3(
    const float* __restrict__ x, const float* __restrict__ agg,
    const int* __restrict__ edges, const float* __restrict__ high,
    const float* __restrict__ Wmu,  const float* __restrict__ bmu,
    const float* __restrict__ Wsig, const float* __restrict__ bsig,
    const float* __restrict__ Wmu2, const float* __restrict__ bmu2,
    const float* __restrict__ Wsig2,const float* __restrict__ bsig2,
    float* __restrict__ out)
{
    const int b = blockIdx.x, t = threadIdx.x;
    __shared__ float sx[64][68];
    __shared__ float sa[64][260];
    __shared__ float su[64][4];
    __shared__ float su2[8][2];

    for (int i = t; i < 64 * 16; i += 256) {
        const int n = i >> 4, kq = i & 15;
        *(f32x4*)&sx[n][kq * 4] = *(const f32x4*)&x[((size_t)b * 64 + n) * 64 + kq * 4];
    }
    for (int i = t; i < 64 * 64; i += 256) {
        const int n = i >> 6, kq = i & 63;
        *(f32x4*)&sa[n][kq * 4] = *(const f32x4*)&agg[((size_t)b * 64 + n) * 256 + kq * 4];
    }
    __syncthreads();

    {
        const int n = t >> 2, s = t & 3;
        const float* Wp = ((s & 1) ? Wsig : Wmu) + ((s >> 1) ? 320 : 0);
        float z = 0.f;
#pragma unroll
        for (int kq = 0; kq < 16; kq++)
            z += dot4(*(const f32x4*)&sx[n][kq * 4], *(const f32x4*)&Wp[kq * 4]);
#pragma unroll 8
        for (int kq = 0; kq < 64; kq++)
            z += dot4(*(const f32x4*)&sa[n][kq * 4], *(const f32x4*)&Wp[64 + kq * 4]);
        su[n][s] = z;
    }
    if (t < 16) {
        const int n = 56 + (t >> 1), s = t & 1;
        const float* Wp = s ? Wsig2 : Wmu2;
        float z = 0.f;
#pragma unroll
        for (int kq = 0; kq < 16; kq++)
            z += dot4(*(const f32x4*)&sx[n][kq * 4], *(const f32x4*)&Wp[kq * 4]);
#pragma unroll 8
        for (int kq = 0; kq < 64; kq++)
            z += dot4(*(const f32x4*)&sa[n][kq * 4], *(const f32x4*)&Wp[64 + kq * 4]);
        su2[n - 56][s] = z;
    }
    __syncthreads();

    if (t < 128) {
        const int e0 = edges[t * 2], e1 = edges[t * 2 + 1];
        const float a  = softplus_f(su[e0][0] + su[e1][2] + bmu[0])  + 1e-20f;
        const float be = softplus_f(su[e0][1] + su[e1][3] + bsig[0]) + 1e-20f;
        out[(size_t)b * 136 + t] = a / (a + be) * high[t];
    } else if (t < 136) {
        const int j = t - 128;
        const float a  = softplus_f(su2[j][0] + bmu2[0])  + 1e-20f;
        const float be = softplus_f(su2[j][1] + bsig2[0]) + 1e-20f;
        out[(size_t)b * 136 + t] = a / (a + be) * high[128 + j];
    }
}

// ---------------------------------------------------------------------------
extern "C" void kernel_launch(void* const* d_in, const int* in_sizes, int n_in,
                              void* d_out, int out_size, void* d_ws, size_t ws_size,
                              hipStream_t stream) {
    const float* x     = (const float*)d_in[0];
    const int*   eidx  = (const int*)  d_in[1];
    const float* ea    = (const float*)d_in[2];
    const int*   edges = (const int*)  d_in[3];
    const float* high  = (const float*)d_in[4];
    const float* W1    = (const float*)d_in[5];
    const float* b1    = (const float*)d_in[6];
    const float* W2    = (const float*)d_in[7];
    const float* b2    = (const float*)d_in[8];
    const float* Wmu   = (const float*)d_in[9];
    const float* bmu   = (const float*)d_in[10];
    const float* Wsig  = (const float*)d_in[11];
    const float* bsig  = (const float*)d_in[12];
    const float* Wmu2  = (const float*)d_in[13];
    const float* bmu2  = (const float*)d_in[14];
    const float* Wsig2 = (const float*)d_in[15];
    const float* bsig2 = (const float*)d_in[16];
    float* out = (float*)d_out;

    // ws: xw (33.55 MB) | sumh1 (16.78 MB) | ... | frags (416 KB at tail)
    // agg aliases xw (dead after k_edges4).
    float* xw    = (float*)d_ws;
    float* sumh1 = xw + (size_t)NTOT * 512;
    float* agg   = xw;
    const size_t frag_off = (ws_size - (size_t)208 * 2048) & ~(size_t)1023;
    unsigned short* frags = (unsigned short*)((char*)d_ws + frag_off);
    const int* dst = eidx + ETOT;

    hipLaunchKernelGGL(k_prep,   dim3(208),    dim3(256),  0, stream, W1, W2, frags);
    hipLaunchKernelGGL(k_xw2,    dim3(256),    dim3(512),  0, stream, x, frags, xw);
    hipLaunchKernelGGL(k_edges4, dim3(BATCH_), dim3(1024), 0, stream,
                       xw, ea, dst, b1, frags, sumh1);
    hipLaunchKernelGGL(k_agg3,   dim3(256),    dim3(512),  0, stream,
                       sumh1, frags, b2, agg);
    hipLaunchKernelGGL(k_head3,  dim3(BATCH_), dim3(256),  0, stream,
                       x, agg, edges, high,
                       Wmu, bmu, Wsig, bsig, Wmu2, bmu2, Wsig2, bsig2, out);
}

// Round 5
// 133.854 us; speedup vs baseline: 1.7232x; 1.2805x over previous
//
#include <hip/hip_runtime.h>
#include <math.h>

#define BATCH_  256
#define ETOT    524288

typedef __attribute__((ext_vector_type(8))) short short8v;
typedef __attribute__((ext_vector_type(4))) float f32x4;

#define MFMA16(a,b,c) __builtin_amdgcn_mfma_f32_16x16x32_bf16((a),(b),(c),0,0,0)

__device__ __forceinline__ unsigned short f2bf(float f) {
    unsigned int x = __float_as_uint(f);
    return (unsigned short)((x + 0x7fffu + ((x >> 16) & 1u)) >> 16);
}
__device__ __forceinline__ float bf2f(unsigned short h) {
    return __uint_as_float(((unsigned int)h) << 16);
}
__device__ __forceinline__ float softplus_f(float v) {
    return v > 20.f ? v : log1pf(expf(v));
}
__device__ __forceinline__ float dot4(f32x4 a, f32x4 b) {
    float z = a[0] * b[0];
    z = fmaf(a[1], b[1], z);
    z = fmaf(a[2], b[2], z);
    z = fmaf(a[3], b[3], z);
    return z;
}
__device__ __forceinline__ void packfrag(f32x4 a, f32x4 q, short8v& hi, short8v& lo) {
    float v[8] = {a[0], a[1], a[2], a[3], q[0], q[1], q[2], q[3]};
#pragma unroll
    for (int j = 0; j < 8; j++) {
        const unsigned short h = f2bf(v[j]);
        hi[j] = (short)h;
        lo[j] = (short)f2bf(v[j] - bf2f(h));
    }
}

// ---------------------------------------------------------------------------
// K0: pre-pack split-bf16 (hi/lo) MFMA A-fragments of W1 (160x256, kt 0..4)
// and W2 (256x256, kt 0..7). Unit u = kt*16 + cht (W1: u 0..79; W2: u 80..207),
// 1024 shorts each: frags[u*1024 + hl*512 + l*8 + j] =
//   W[(kt*32 + (l>>4)*8 + j) * 256 + cht*16 + (l&15)]  (hi at hl=0, lo at hl=1)
// ---------------------------------------------------------------------------
__global__ __launch_bounds__(256) void k_prep(const float* __restrict__ W1,
                                              const float* __restrict__ W2,
                                              unsigned short* __restrict__ frags) {
    const int u = blockIdx.x;
    const float* S = (u < 80) ? W1 : W2;
    const int ul = (u < 80) ? u : (u - 80);
    const int rowbase = (ul >> 4) * 32;
    const int cht = ul & 15;
    for (int idx = threadIdx.x; idx < 512; idx += 256) {
        const int l = idx >> 3, j = idx & 7;
        const int row = rowbase + ((l >> 4) << 3) + j;
        const int col = cht * 16 + (l & 15);
        const float v = S[row * 256 + col];
        const unsigned short h = f2bf(v);
        frags[u * 1024 + idx]       = h;
        frags[u * 1024 + 512 + idx] = f2bf(v - bf2f(h));
    }
}

// ---------------------------------------------------------------------------
// K1: the whole network per batch. Block = 1 batch, 1024 thr (16 waves),
// __launch_bounds__(1024,4) -> 128-VGPR budget (no spills).
//
// LDS (131072 B, region-reused):
//   R1 [0..64K):    s_xwb[64][256] (A,B)  -> s_sumh1[64][256] (B..C) -> s_su (D)
//   R2 [64K..96K):  s_ea[4][2][4][64][8] (B) -> s_agg first half (C,D)
//   R3 [96K..128K): s_dstl[2048] (B)         -> s_agg second half (C,D)
// All [64][256] tiles XOR-swizzled: col' = col ^ ((row&7)<<2).
//
// Phase A: x^T frags (global) -> xab1 = x@W1a + b1 (MFMA, C-init=b1, regs)
//          and s_xwb = x@W1b (MFMA, transposed write to LDS).
// Phase B: offset loop o=0..31 (8 chunks x 4): D = W1c^T . ea_o^T (+xab1 via
//          C-operand), acc += relu(D + s_xwb[dst]); ea hi/lo double-staged.
// Phase C: agg = sumh1 @ W2 + 32*b2, wave = 2 row-tiles x 2 col-tiles.
// Phase D: heads (factored u/v dots from s_agg + global x) -> out.
// ---------------------------------------------------------------------------
__global__ __launch_bounds__(1024, 4) void k_fused(
    const float* __restrict__ x, const float* __restrict__ ea,
    const int* __restrict__ dst, const int* __restrict__ edges,
    const float* __restrict__ high, const float* __restrict__ b1,
    const float* __restrict__ b2, const unsigned short* __restrict__ frags,
    const float* __restrict__ Wmu,  const float* __restrict__ bmu,
    const float* __restrict__ Wsig, const float* __restrict__ bsig,
    const float* __restrict__ Wmu2, const float* __restrict__ bmu2,
    const float* __restrict__ Wsig2,const float* __restrict__ bsig2,
    float* __restrict__ out)
{
    __shared__ __align__(16) unsigned char smem[131072];
    float*          s_xwb   = (float*)smem;                       // [64][256]
    unsigned short* s_ea    = (unsigned short*)(smem + 65536);    // [4][2][4][64][8]
    unsigned char*  s_dstl  = (unsigned char*)(smem + 98304);     // [2048]
    float*          s_sumh1 = (float*)smem;                       // [64][256]
    float*          s_agg   = (float*)(smem + 65536);             // [64][256]
    float*          s_su    = (float*)smem;                       // [64][4]
    float*          s_su2   = (float*)(smem + 1024);              // [8][2]

    const int b = blockIdx.x, tid = threadIdx.x;
    const int l = tid & 63, w = tid >> 6, g = l >> 4, l15 = l & 15;
    const int ng = w & 3, cq = w >> 2;
    const int node = ng * 16 + l15;
    const int swzn = (l15 & 7) << 2;   // == ((node or row)&7)<<2 for row%16==l15

    // ---- dst staging + ea staging geometry + prologue loads
    for (int idx = tid; idx < 2048; idx += 1024)
        s_dstl[idx] = (unsigned char)(dst[b * 2048 + idx] & 63);

    const int ols = tid >> 8, ns = (tid & 255) >> 2, ko = tid & 3;
    const int sll = (ko << 4) | (ns & 15), sng = ns >> 4;
    const float* eab = ea + (size_t)b * 65536 + (size_t)ns * 1024 + ko * 8;
    f32x4 ld0 = *(const f32x4*)&eab[ols * 32];
    f32x4 ld1 = *(const f32x4*)&eab[ols * 32 + 4];

    // ================= phase A =================
    short8v Xh[2], Xl[2];
#pragma unroll
    for (int kt = 0; kt < 2; kt++) {
        const float* p = x + (size_t)(b * 64 + node) * 64 + kt * 32 + g * 8;
        packfrag(*(const f32x4*)p, *(const f32x4*)(p + 4), Xh[kt], Xl[kt]);
    }

    f32x4 xab1[4];
#pragma unroll
    for (int i = 0; i < 4; i++) {
        const int cht = cq * 4 + i;
        f32x4 d = *(const f32x4*)&b1[cht * 16 + g * 4];   // C-init = b1
#pragma unroll
        for (int kt = 0; kt < 2; kt++) {
            const int base = (kt * 16 + cht) * 1024 + l * 8;
            const short8v Ah = *(const short8v*)&frags[base];
            const short8v Al = *(const short8v*)&frags[base + 512];
            d = MFMA16(Al, Xh[kt], d);
            d = MFMA16(Ah, Xl[kt], d);
            d = MFMA16(Ah, Xh[kt], d);
        }
        xab1[i] = d;
    }

#pragma unroll
    for (int i = 0; i < 4; i++) {
        const int cht = cq * 4 + i;
        f32x4 d = {0.f, 0.f, 0.f, 0.f};
#pragma unroll
        for (int kt = 0; kt < 2; kt++) {
            const int base = ((kt + 2) * 16 + cht) * 1024 + l * 8;
            const short8v Ah = *(const short8v*)&frags[base];
            const short8v Al = *(const short8v*)&frags[base + 512];
            d = MFMA16(Al, Xh[kt], d);
            d = MFMA16(Ah, Xl[kt], d);
            d = MFMA16(Ah, Xh[kt], d);
        }
        // D[ch][node]: lane col = node (own group), rows cht*16+g*4..+3
        *(f32x4*)&s_xwb[node * 256 + ((cht * 16 + g * 4) ^ swzn)] = d;
    }

    // W1c A-frags for phase B (units 64..79)
    short8v Ah[4], Al[4];
#pragma unroll
    for (int i = 0; i < 4; i++) {
        const int base = (64 + cq * 4 + i) * 1024 + l * 8;
        Ah[i] = *(const short8v*)&frags[base];
        Al[i] = *(const short8v*)&frags[base + 512];
    }

    f32x4 acc[4];
#pragma unroll
    for (int i = 0; i < 4; i++) acc[i] = (f32x4){0.f, 0.f, 0.f, 0.f};

    // ================= phase B =================
    for (int c = 0; c < 8; c++) {
        short8v hi, lo;
        packfrag(ld0, ld1, hi, lo);
        __syncthreads();   // prev chunk consumed (c=0: phase-A LDS writes done)
        *(short8v*)&s_ea[(((ols * 2 + 0) * 4 + sng) * 64 + sll) * 8] = hi;
        *(short8v*)&s_ea[(((ols * 2 + 1) * 4 + sng) * 64 + sll) * 8] = lo;
        __syncthreads();   // chunk visible (and xwb visible at c=0)

        if (c < 7) {
            const int on = (c + 1) * 4 + ols;
            ld0 = *(const f32x4*)&eab[on * 32];
            ld1 = *(const f32x4*)&eab[on * 32 + 4];
        }

        const unsigned int dwc = ((const unsigned int*)s_dstl)[node * 8 + c];

#pragma unroll
        for (int ol = 0; ol < 4; ol++) {
            const short8v Bh = *(const short8v*)&s_ea[(((ol * 2 + 0) * 4 + ng) * 64 + l) * 8];
            const short8v Bl = *(const short8v*)&s_ea[(((ol * 2 + 1) * 4 + ng) * 64 + l) * 8];
            const int d = (dwc >> (ol * 8)) & 0xFF;
            const int swz = (d & 7) << 2;

#pragma unroll
            for (int i = 0; i < 4; i++) {
                const int cb = cq * 64 + i * 16 + g * 4;
                const f32x4 wb = *(const f32x4*)&s_xwb[d * 256 + (cb ^ swz)];
                f32x4 di = MFMA16(Al[i], Bh, xab1[i]);
                di = MFMA16(Ah[i], Bl, di);
                di = MFMA16(Ah[i], Bh, di);
#pragma unroll
                for (int r = 0; r < 4; r++)
                    acc[i][r] += fmaxf(di[r] + wb[r], 0.f);
            }
        }
    }

    __syncthreads();   // all xwb gathers / ea reads done -> R1 reusable
#pragma unroll
    for (int i = 0; i < 4; i++)
        *(f32x4*)&s_sumh1[node * 256 + ((cq * 64 + i * 16 + g * 4) ^ swzn)] = acc[i];
    __syncthreads();   // sumh1 visible; ea/dst regions dead

    // ================= phase C =================
    const int rp = w & 1, ocp = w >> 1;   // wave = 2 row-tiles x 2 col-tiles
    f32x4 acc2[2][2];
#pragma unroll
    for (int rti = 0; rti < 2; rti++)
#pragma unroll
        for (int oci = 0; oci < 2; oci++)
            acc2[rti][oci] = (f32x4){0.f, 0.f, 0.f, 0.f};

    for (int ks = 0; ks < 8; ks++) {
        short8v Ahh[2], All[2];
#pragma unroll
        for (int rti = 0; rti < 2; rti++) {
            const int row = (rp * 2 + rti) * 16 + l15;
            const int cb = ks * 32 + g * 8;
            const f32x4 a0 = *(const f32x4*)&s_sumh1[row * 256 + (cb ^ swzn)];
            const f32x4 a1 = *(const f32x4*)&s_sumh1[row * 256 + ((cb + 4) ^ swzn)];
            packfrag(a0, a1, Ahh[rti], All[rti]);
        }
#pragma unroll
        for (int oci = 0; oci < 2; oci++) {
            const int base = (80 + ks * 16 + ocp * 2 + oci) * 1024 + l * 8;
            const short8v Bh = *(const short8v*)&frags[base];
            const short8v Bl = *(const short8v*)&frags[base + 512];
#pragma unroll
            for (int rti = 0; rti < 2; rti++) {
                acc2[rti][oci] = MFMA16(Ahh[rti], Bh, acc2[rti][oci]);
                acc2[rti][oci] = MFMA16(Ahh[rti], Bl, acc2[rti][oci]);
                acc2[rti][oci] = MFMA16(All[rti], Bh, acc2[rti][oci]);
            }
        }
    }

    // epilogue: agg[row][col] + 32*b2[col] into s_agg (swizzled)
#pragma unroll
    for (int rti = 0; rti < 2; rti++) {
#pragma unroll
        for (int oci = 0; oci < 2; oci++) {
            const int col = (ocp * 2 + oci) * 16 + l15;
            const float bb = 32.f * b2[col];
#pragma unroll
            for (int r = 0; r < 4; r++) {
                const int row = (rp * 2 + rti) * 16 + g * 4 + r;
                s_agg[row * 256 + (col ^ ((row & 7) << 2))] = acc2[rti][oci][r] + bb;
            }
        }
    }
    __syncthreads();   // agg ready; sumh1 reads done -> R1 reusable for su

    // ================= phase D =================
    if (tid < 256) {
        const int n = tid >> 2, s = tid & 3;
        const float* Wp = ((s & 1) ? Wsig : Wmu) + ((s >> 1) ? 320 : 0);
        const float* xr = x + (size_t)(b * 64 + n) * 64;
        const int sw = (n & 7) << 2;
        float z = 0.f;
#pragma unroll
        for (int kq = 0; kq < 16; kq++)
            z += dot4(*(const f32x4*)&xr[kq * 4], *(const f32x4*)&Wp[kq * 4]);
#pragma unroll 8
        for (int kq = 0; kq < 64; kq++)
            z += dot4(*(const f32x4*)&s_agg[n * 256 + ((kq * 4) ^ sw)],
                      *(const f32x4*)&Wp[64 + kq * 4]);
        s_su[n * 4 + s] = z;
    }
    if (tid < 16) {
        const int n = 56 + (tid >> 1), s = tid & 1;
        const float* Wp = s ? Wsig2 : Wmu2;
        const float* xr = x + (size_t)(b * 64 + n) * 64;
        const int sw = (n & 7) << 2;
        float z = 0.f;
#pragma unroll
        for (int kq = 0; kq < 16; kq++)
            z += dot4(*(const f32x4*)&xr[kq * 4], *(const f32x4*)&Wp[kq * 4]);
#pragma unroll 8
        for (int kq = 0; kq < 64; kq++)
            z += dot4(*(const f32x4*)&s_agg[n * 256 + ((kq * 4) ^ sw)],
                      *(const f32x4*)&Wp[64 + kq * 4]);
        s_su2[(n - 56) * 2 + s] = z;
    }
    __syncthreads();

    if (tid < 128) {
        const int e0 = edges[tid * 2], e1 = edges[tid * 2 + 1];
        const float a  = softplus_f(s_su[e0 * 4 + 0] + s_su[e1 * 4 + 2] + bmu[0])  + 1e-20f;
        const float be = softplus_f(s_su[e0 * 4 + 1] + s_su[e1 * 4 + 3] + bsig[0]) + 1e-20f;
        out[(size_t)b * 136 + tid] = a / (a + be) * high[tid];
    } else if (tid < 136) {
        const int j = tid - 128;
        const float a  = softplus_f(s_su2[j * 2 + 0] + bmu2[0])  + 1e-20f;
        const float be = softplus_f(s_su2[j * 2 + 1] + bsig2[0]) + 1e-20f;
        out[(size_t)b * 136 + tid] = a / (a + be) * high[128 + j];
    }
}

// ---------------------------------------------------------------------------
extern "C" void kernel_launch(void* const* d_in, const int* in_sizes, int n_in,
                              void* d_out, int out_size, void* d_ws, size_t ws_size,
                              hipStream_t stream) {
    const float* x     = (const float*)d_in[0];
    const int*   eidx  = (const int*)  d_in[1];
    const float* ea    = (const float*)d_in[2];
    const int*   edges = (const int*)  d_in[3];
    const float* high  = (const float*)d_in[4];
    const float* W1    = (const float*)d_in[5];
    const float* b1    = (const float*)d_in[6];
    const float* W2    = (const float*)d_in[7];
    const float* b2    = (const float*)d_in[8];
    const float* Wmu   = (const float*)d_in[9];
    const float* bmu   = (const float*)d_in[10];
    const float* Wsig  = (const float*)d_in[11];
    const float* bsig  = (const float*)d_in[12];
    const float* Wmu2  = (const float*)d_in[13];
    const float* bmu2  = (const float*)d_in[14];
    const float* Wsig2 = (const float*)d_in[15];
    const float* bsig2 = (const float*)d_in[16];
    float* out = (float*)d_out;

    // ws: only the pre-packed weight fragments (208 units x 2 KB = 416 KB)
    const size_t frag_off = (ws_size - (size_t)208 * 2048) & ~(size_t)1023;
    unsigned short* frags = (unsigned short*)((char*)d_ws + frag_off);
    const int* dst = eidx + ETOT;

    hipLaunchKernelGGL(k_prep,  dim3(208),    dim3(256),  0, stream, W1, W2, frags);
    hipLaunchKernelGGL(k_fused, dim3(BATCH_), dim3(1024), 0, stream,
                       x, ea, dst, edges, high, b1, b2, frags,
                       Wmu, bmu, Wsig, bsig, Wmu2, bmu2, Wsig2, bsig2, out);
}

// Round 6
// 73.884 us; speedup vs baseline: 3.1219x; 1.8117x over previous
//
#include <hip/hip_runtime.h>
#include <math.h>

#define BATCH_  256
#define ETOT    524288

typedef __attribute__((ext_vector_type(8))) short short8v;
typedef __attribute__((ext_vector_type(4))) float f32x4;

#define MFMA16(a,b,c) __builtin_amdgcn_mfma_f32_16x16x32_bf16((a),(b),(c),0,0,0)

__device__ __forceinline__ unsigned short f2bf(float f) {
    unsigned int x = __float_as_uint(f);
    return (unsigned short)((x + 0x7fffu + ((x >> 16) & 1u)) >> 16);
}
__device__ __forceinline__ float bf2f(unsigned short h) {
    return __uint_as_float(((unsigned int)h) << 16);
}
__device__ __forceinline__ float softplus_f(float v) {
    return v > 20.f ? v : log1pf(expf(v));
}
__device__ __forceinline__ float dot4(f32x4 a, f32x4 b) {
    float z = a[0] * b[0];
    z = fmaf(a[1], b[1], z);
    z = fmaf(a[2], b[2], z);
    z = fmaf(a[3], b[3], z);
    return z;
}
__device__ __forceinline__ void packfrag(f32x4 a, f32x4 q, short8v& hi, short8v& lo) {
    float v[8] = {a[0], a[1], a[2], a[3], q[0], q[1], q[2], q[3]};
#pragma unroll
    for (int j = 0; j < 8; j++) {
        const unsigned short h = f2bf(v[j]);
        hi[j] = (short)h;
        lo[j] = (short)f2bf(v[j] - bf2f(h));
    }
}

// ---------------------------------------------------------------------------
// K0: pre-pack split-bf16 (hi/lo) MFMA A-fragments of W1 (160x256, kt 0..4)
// and W2 (256x256, kt 0..7). Unit u = kt*16 + cht (W1: u 0..79; W2: u 80..207),
// 1024 shorts: frags[u*1024 + hl*512 + l*8 + j] =
//   W[(kt*32 + (l>>4)*8 + j) * 256 + cht*16 + (l&15)]
// ---------------------------------------------------------------------------
__global__ __launch_bounds__(256) void k_prep(const float* __restrict__ W1,
                                              const float* __restrict__ W2,
                                              unsigned short* __restrict__ frags) {
    const int u = blockIdx.x;
    const float* S = (u < 80) ? W1 : W2;
    const int ul = (u < 80) ? u : (u - 80);
    const int rowbase = (ul >> 4) * 32;
    const int cht = ul & 15;
    for (int idx = threadIdx.x; idx < 512; idx += 256) {
        const int l = idx >> 3, j = idx & 7;
        const int row = rowbase + ((l >> 4) << 3) + j;
        const int col = cht * 16 + (l & 15);
        const float v = S[row * 256 + col];
        const unsigned short h = f2bf(v);
        frags[u * 1024 + idx]       = h;
        frags[u * 1024 + 512 + idx] = f2bf(v - bf2f(h));
    }
}

// ---------------------------------------------------------------------------
// K1: whole network per batch. Block = 1 batch, 512 thr (8 waves, 2/SIMD),
// waves_per_eu(2) -> 256-VGPR budget (state ~170, no spill).
// Wave (ng=w&3, cq=w>>2): 16 nodes (ng) x 128 channels (cq half).
//
// LDS (131072 B, region-reused):
//   R1 [0..64K):     s_xwb[64][256] (A,B) -> s_sumh1 (B..C) -> s_su (D)
//   R2 [64K..96K):   s_ea dbuf [2][2][2][4][64][8] (B) -> s_agg[0:32K] (C,D)
//   R3 [96K..128K):  s_dstl @98304 (B)                 -> s_agg[32K:64K] (C,D)
// [64][256] f32 tiles XOR-swizzled: col' = col ^ ((row&7)<<2).
// ---------------------------------------------------------------------------
__global__ __launch_bounds__(512) __attribute__((amdgpu_waves_per_eu(2)))
void k_fused(
    const float* __restrict__ x, const float* __restrict__ ea,
    const int* __restrict__ dst, const int* __restrict__ edges,
    const float* __restrict__ high, const float* __restrict__ b1,
    const float* __restrict__ b2, const unsigned short* __restrict__ frags,
    const float* __restrict__ Wmu,  const float* __restrict__ bmu,
    const float* __restrict__ Wsig, const float* __restrict__ bsig,
    const float* __restrict__ Wmu2, const float* __restrict__ bmu2,
    const float* __restrict__ Wsig2,const float* __restrict__ bsig2,
    float* __restrict__ out)
{
    __shared__ __align__(16) unsigned char smem[131072];
    float*          s_xwb   = (float*)smem;                      // [64][256]
    unsigned short* s_ea    = (unsigned short*)(smem + 65536);   // [2][2][2][4][64][8]
    unsigned char*  s_dstl  = (unsigned char*)(smem + 98304);    // [2048]
    float*          s_sumh1 = (float*)smem;                      // [64][256]
    float*          s_agg   = (float*)(smem + 65536);            // [64][256]
    float*          s_su    = (float*)smem;                      // [64][4]
    float*          s_su2   = (float*)(smem + 1024);             // [8][2]

    const int b = blockIdx.x, tid = threadIdx.x;
    const int l = tid & 63, w = tid >> 6, g = l >> 4, l15 = l & 15;
    const int ng = w & 3, cq = w >> 2;            // cq in {0,1}
    const int node = ng * 16 + l15;
    const int swzn = (l15 & 7) << 2;

    // ---- dst staging
    for (int idx = tid; idx < 2048; idx += 512)
        s_dstl[idx] = (unsigned char)(dst[b * 2048 + idx] & 63);

    // ---- ea staging geometry: chunk = 2 offset-slices; thread -> (ols, ns, ko)
    const int ols = tid >> 8;                 // slice-in-chunk 0..1
    const int ns  = (tid & 255) >> 2;         // node 0..63
    const int ko  = tid & 3;                  // k-octet
    const int sll = (ko << 4) | (ns & 15), sng = ns >> 4;
    const float* eab = ea + (size_t)b * 65536 + (size_t)ns * 1024 + ko * 8;

    // chunk 0 loads (slice o = ols) issued before phase A for overlap
    f32x4 ld0 = *(const f32x4*)&eab[(size_t)ols * 32];
    f32x4 ld1 = *(const f32x4*)&eab[(size_t)ols * 32 + 4];

    // ================= phase A =================
    short8v Xh[2], Xl[2];
#pragma unroll
    for (int kt = 0; kt < 2; kt++) {
        const float* p = x + (size_t)(b * 64 + node) * 64 + kt * 32 + g * 8;
        packfrag(*(const f32x4*)p, *(const f32x4*)(p + 4), Xh[kt], Xl[kt]);
    }

    f32x4 xab1[8];
#pragma unroll
    for (int i = 0; i < 8; i++) {
        const int cht = cq * 8 + i;
        f32x4 d = *(const f32x4*)&b1[cht * 16 + g * 4];   // C-init = b1
#pragma unroll
        for (int kt = 0; kt < 2; kt++) {
            const int base = (kt * 16 + cht) * 1024 + l * 8;
            const short8v Ahh = *(const short8v*)&frags[base];
            const short8v All = *(const short8v*)&frags[base + 512];
            d = MFMA16(All, Xh[kt], d);
            d = MFMA16(Ahh, Xl[kt], d);
            d = MFMA16(Ahh, Xh[kt], d);
        }
        xab1[i] = d;
    }

#pragma unroll
    for (int i = 0; i < 8; i++) {
        const int cht = cq * 8 + i;
        f32x4 d = {0.f, 0.f, 0.f, 0.f};
#pragma unroll
        for (int kt = 0; kt < 2; kt++) {
            const int base = ((kt + 2) * 16 + cht) * 1024 + l * 8;
            const short8v Ahh = *(const short8v*)&frags[base];
            const short8v All = *(const short8v*)&frags[base + 512];
            d = MFMA16(All, Xh[kt], d);
            d = MFMA16(Ahh, Xl[kt], d);
            d = MFMA16(Ahh, Xh[kt], d);
        }
        *(f32x4*)&s_xwb[node * 256 + ((cht * 16 + g * 4) ^ swzn)] = d;
    }

    // W1c A-frags (units 64..79), register-cached
    short8v Ah[8], Al[8];
#pragma unroll
    for (int i = 0; i < 8; i++) {
        const int base = (64 + cq * 8 + i) * 1024 + l * 8;
        Ah[i] = *(const short8v*)&frags[base];
        Al[i] = *(const short8v*)&frags[base + 512];
    }

    // stage chunk 0 into buf 0, then issue chunk 1 loads
    {
        short8v hi, lo;
        packfrag(ld0, ld1, hi, lo);
        *(short8v*)&s_ea[((((0 * 2 + 0) * 2 + ols) * 4 + sng) * 64 + sll) * 8] = hi;
        *(short8v*)&s_ea[((((0 * 2 + 1) * 2 + ols) * 4 + sng) * 64 + sll) * 8] = lo;
    }
    ld0 = *(const f32x4*)&eab[(size_t)(2 + ols) * 32];
    ld1 = *(const f32x4*)&eab[(size_t)(2 + ols) * 32 + 4];
    __syncthreads();   // xwb + dstl + ea chunk0 visible

    f32x4 acc[8];
#pragma unroll
    for (int i = 0; i < 8; i++) acc[i] = (f32x4){0.f, 0.f, 0.f, 0.f};

    // ================= phase B ================= (16 chunks x 2 offsets)
    for (int c = 0; c < 16; ++c) {
        if (c < 15) {   // store next chunk into other buffer (overlaps consume)
            short8v hi, lo;
            packfrag(ld0, ld1, hi, lo);
            const int nb = (c + 1) & 1;
            *(short8v*)&s_ea[((((nb * 2 + 0) * 2 + ols) * 4 + sng) * 64 + sll) * 8] = hi;
            *(short8v*)&s_ea[((((nb * 2 + 1) * 2 + ols) * 4 + sng) * 64 + sll) * 8] = lo;
            if (c < 14) {
                const int o = (c + 2) * 2 + ols;
                ld0 = *(const f32x4*)&eab[(size_t)o * 32];
                ld1 = *(const f32x4*)&eab[(size_t)o * 32 + 4];
            }
        }

        const int cb2 = c & 1;
        const unsigned short dw = ((const unsigned short*)s_dstl)[node * 16 + c];

#pragma unroll
        for (int ol = 0; ol < 2; ol++) {
            const short8v Bh = *(const short8v*)&s_ea[((((cb2 * 2 + 0) * 2 + ol) * 4 + ng) * 64 + l) * 8];
            const short8v Bl = *(const short8v*)&s_ea[((((cb2 * 2 + 1) * 2 + ol) * 4 + ng) * 64 + l) * 8];
            const int d = (dw >> (ol * 8)) & 0xFF;
            const int swz = (d & 7) << 2;

#pragma unroll
            for (int i = 0; i < 8; i++) {
                const int cb = cq * 128 + i * 16 + g * 4;
                const f32x4 wb = *(const f32x4*)&s_xwb[d * 256 + (cb ^ swz)];
                f32x4 di = MFMA16(Al[i], Bh, xab1[i]);
                di = MFMA16(Ah[i], Bl, di);
                di = MFMA16(Ah[i], Bh, di);
#pragma unroll
                for (int r = 0; r < 4; r++)
                    acc[i][r] += fmaxf(di[r] + wb[r], 0.f);
            }
        }
        __syncthreads();   // chunk consumed by all; next-buf stores visible
    }

    // sumh1 into R1 (xwb dead)
#pragma unroll
    for (int i = 0; i < 8; i++)
        *(f32x4*)&s_sumh1[node * 256 + ((cq * 128 + i * 16 + g * 4) ^ swzn)] = acc[i];
    __syncthreads();

    // ================= phase C =================  wave = (rt = w&3, ch8 = w>>2)
    const int rt = w & 3, ch8 = w >> 2;
    f32x4 acc2[8];
#pragma unroll
    for (int j = 0; j < 8; j++) acc2[j] = (f32x4){0.f, 0.f, 0.f, 0.f};

    for (int ks = 0; ks < 8; ks++) {
        const int row = rt * 16 + l15;
        const int cbk = ks * 32 + g * 8;
        const f32x4 a0 = *(const f32x4*)&s_sumh1[row * 256 + (cbk ^ swzn)];
        const f32x4 a1 = *(const f32x4*)&s_sumh1[row * 256 + ((cbk + 4) ^ swzn)];
        short8v Ahh, All;
        packfrag(a0, a1, Ahh, All);
#pragma unroll
        for (int j = 0; j < 8; j++) {
            const int base = (80 + ks * 16 + ch8 * 8 + j) * 1024 + l * 8;
            const short8v Bh = *(const short8v*)&frags[base];
            const short8v Bl = *(const short8v*)&frags[base + 512];
            acc2[j] = MFMA16(Ahh, Bh, acc2[j]);
            acc2[j] = MFMA16(Ahh, Bl, acc2[j]);
            acc2[j] = MFMA16(All, Bh, acc2[j]);
        }
    }

#pragma unroll
    for (int j = 0; j < 8; j++) {
        const int col = (ch8 * 8 + j) * 16 + l15;
        const float bb = 32.f * b2[col];
#pragma unroll
        for (int r = 0; r < 4; r++) {
            const int row = rt * 16 + g * 4 + r;
            s_agg[row * 256 + (col ^ ((row & 7) << 2))] = acc2[j][r] + bb;
        }
    }
    __syncthreads();   // agg ready; sumh1 reads done -> R1 free for su

    // ================= phase D =================
    if (tid < 256) {
        const int n = tid >> 2, s = tid & 3;
        const float* Wp = ((s & 1) ? Wsig : Wmu) + ((s >> 1) ? 320 : 0);
        const float* xr = x + (size_t)(b * 64 + n) * 64;
        const int sw = (n & 7) << 2;
        float z = 0.f;
#pragma unroll
        for (int kq = 0; kq < 16; kq++)
            z += dot4(*(const f32x4*)&xr[kq * 4], *(const f32x4*)&Wp[kq * 4]);
#pragma unroll 8
        for (int kq = 0; kq < 64; kq++)
            z += dot4(*(const f32x4*)&s_agg[n * 256 + ((kq * 4) ^ sw)],
                      *(const f32x4*)&Wp[64 + kq * 4]);
        s_su[n * 4 + s] = z;
    } else if (tid < 272) {
        const int j = (tid - 256) >> 1, s = tid & 1;
        const int n = 56 + j;
        const float* Wp = s ? Wsig2 : Wmu2;
        const float* xr = x + (size_t)(b * 64 + n) * 64;
        const int sw = (n & 7) << 2;
        float z = 0.f;
#pragma unroll
        for (int kq = 0; kq < 16; kq++)
            z += dot4(*(const f32x4*)&xr[kq * 4], *(const f32x4*)&Wp[kq * 4]);
#pragma unroll 8
        for (int kq = 0; kq < 64; kq++)
            z += dot4(*(const f32x4*)&s_agg[n * 256 + ((kq * 4) ^ sw)],
                      *(const f32x4*)&Wp[64 + kq * 4]);
        s_su2[j * 2 + s] = z;
    }
    __syncthreads();

    if (tid < 128) {
        const int e0 = edges[tid * 2], e1 = edges[tid * 2 + 1];
        const float a  = softplus_f(s_su[e0 * 4 + 0] + s_su[e1 * 4 + 2] + bmu[0])  + 1e-20f;
        const float be = softplus_f(s_su[e0 * 4 + 1] + s_su[e1 * 4 + 3] + bsig[0]) + 1e-20f;
        out[(size_t)b * 136 + tid] = a / (a + be) * high[tid];
    } else if (tid < 136) {
        const int j = tid - 128;
        const float a  = softplus_f(s_su2[j * 2 + 0] + bmu2[0])  + 1e-20f;
        const float be = softplus_f(s_su2[j * 2 + 1] + bsig2[0]) + 1e-20f;
        out[(size_t)b * 136 + tid] = a / (a + be) * high[128 + j];
    }
}

// ---------------------------------------------------------------------------
extern "C" void kernel_launch(void* const* d_in, const int* in_sizes, int n_in,
                              void* d_out, int out_size, void* d_ws, size_t ws_size,
                              hipStream_t stream) {
    const float* x     = (const float*)d_in[0];
    const int*   eidx  = (const int*)  d_in[1];
    const float* ea    = (const float*)d_in[2];
    const int*   edges = (const int*)  d_in[3];
    const float* high  = (const float*)d_in[4];
    const float* W1    = (const float*)d_in[5];
    const float* b1    = (const float*)d_in[6];
    const float* W2    = (const float*)d_in[7];
    const float* b2    = (const float*)d_in[8];
    const float* Wmu   = (const float*)d_in[9];
    const float* bmu   = (const float*)d_in[10];
    const float* Wsig  = (const float*)d_in[11];
    const float* bsig  = (const float*)d_in[12];
    const float* Wmu2  = (const float*)d_in[13];
    const float* bmu2  = (const float*)d_in[14];
    const float* Wsig2 = (const float*)d_in[15];
    const float* bsig2 = (const float*)d_in[16];
    float* out = (float*)d_out;

    // ws: pre-packed weight fragments only (208 units x 2 KB = 416 KB)
    const size_t frag_off = (ws_size - (size_t)208 * 2048) & ~(size_t)1023;
    unsigned short* frags = (unsigned short*)((char*)d_ws + frag_off);
    const int* dst = eidx + ETOT;

    hipLaunchKernelGGL(k_prep,  dim3(208),    dim3(256), 0, stream, W1, W2, frags);
    hipLaunchKernelGGL(k_fused, dim3(BATCH_), dim3(512), 0, stream,
                       x, ea, dst, edges, high, b1, b2, frags,
                       Wmu, bmu, Wsig, bsig, Wmu2, bmu2, Wsig2, bsig2, out);
}